// Round 9
// baseline (209.032 us; speedup 1.0000x reference)
//
#include <hip/hip_runtime.h>
#include <math.h>

#define D_MODEL 1024
#define N_HEADS 16
#define HEAD_DIM 64
#define SEQ_T 2048
#define BATCH 2

typedef __attribute__((ext_vector_type(8))) short short8;
typedef __attribute__((ext_vector_type(4))) float f32x4;

__device__ __forceinline__ unsigned short f2bf(float f) {
    union { float f; unsigned int u; } v; v.f = f;
    return (unsigned short)((v.u + 0x7FFFu + ((v.u >> 16) & 1u)) >> 16);
}

// cheap round-half-up pack (P matrix only; values >= 0)
__device__ __forceinline__ unsigned short f2bf_fast(float f) {
    union { float f; unsigned int u; } v; v.f = f;
    return (unsigned short)((v.u + 0x8000u) >> 16);
}

__device__ __forceinline__ void glds16(const unsigned short* g, unsigned short* l) {
    __builtin_amdgcn_global_load_lds(
        (const __attribute__((address_space(1))) unsigned int*)g,
        (__attribute__((address_space(3))) unsigned int*)l, 16, 0, 0);
}

// ---------------- fused fp32 -> bf16 convert (x + 4 weights) ----------------
__global__ void cvt_all(const float4* __restrict__ x,
                        const float4* __restrict__ Wq, const float4* __restrict__ Wk,
                        const float4* __restrict__ Wv, const float4* __restrict__ Wp,
                        ushort4* __restrict__ xb, ushort4* __restrict__ wb,
                        ushort4* __restrict__ wpb) {
    int i = blockIdx.x * 256 + threadIdx.x;
    float4 v; ushort4* dst;
    if (i < 1048576) { v = x[i]; dst = xb + i; }
    else {
        int j = i - 1048576;
        int wsel = j >> 18;
        int o = j & 262143;
        const float4* s = wsel == 0 ? Wq : wsel == 1 ? Wk : wsel == 2 ? Wv : Wp;
        v = s[o];
        dst = (wsel == 3) ? (wpb + o) : (wb + (size_t)wsel * 262144 + o);
    }
    ushort4 u;
    u.x = f2bf(v.x); u.y = f2bf(v.y); u.z = f2bf(v.z); u.w = f2bf(v.w);
    *dst = u;
}

// ---------------- GEMM v4: BK=32, fragment-major LDS (conflict-free, 16 KB) ----------------
// LDS holds tiles in MFMA-fragment order: block q, lane l -> A[m0+q*16+(l&15)][k0+(l>>4)*8..+8]
// Staging source is per-lane scattered (free); LDS dest is lane-contiguous (glds16 requirement);
// readers do ds_read_b128 at base+lane*16 -> stride-1, zero bank conflicts.
// MODE 2: fp32 out row-major [M,1024], bias b0
// MODE 3: fused QKV: N=3072; q [B,H,T,Dh]; k [B,H,Tperm,Dh] (32-key permuted); v [B,H,Dh,T]
template<int MODE, int MTILE>
__global__ __launch_bounds__(256) void gemm4(
    const unsigned short* __restrict__ A,
    const unsigned short* __restrict__ W,
    const float* __restrict__ b0, const float* __restrict__ b1, const float* __restrict__ b2,
    void* __restrict__ o0, void* __restrict__ o1, void* __restrict__ o2)
{
    constexpr int K = 1024;
    constexpr int MT = MTILE / 32;      // m-frags per wave
    constexpr int AIW = MTILE / 64;     // A staging issues per wave (16 rows each)
    __shared__ unsigned short As[MTILE * 32];   // fragment-major: MTILE/16 blocks of 512 shorts
    __shared__ unsigned short Bs[128 * 32];
    const int m0 = blockIdx.y * MTILE;
    const int n0 = blockIdx.x * 128;
    const int tid = threadIdx.x;
    const int w = tid >> 6, lane = tid & 63;
    const int col = lane & 15, quad = lane >> 4;
    const int wm = (w & 1) * (MTILE / 2), wn = (w >> 1) * 64;
    const int srow = lane & 15;          // staging source row within 16-row block
    const int schunk = lane >> 4;        // staging source k-chunk (8 shorts)
    const int abase = (w & 1) * MT;      // this wave's first A fragment-block
    const int bbase = (w >> 1) * 4;      // this wave's first B fragment-block

    const f32x4 zero = {0.f, 0.f, 0.f, 0.f};
    f32x4 acc[MT][4];
#pragma unroll
    for (int i = 0; i < MT; i++)
#pragma unroll
        for (int j = 0; j < 4; j++) acc[i][j] = zero;

    for (int k0 = 0; k0 < K; k0 += 32) {
        __syncthreads();
#pragma unroll
        for (int c = 0; c < AIW; c++) {
            const int q = w * AIW + c;
            glds16(&A[(size_t)(m0 + q * 16 + srow) * K + k0 + schunk * 8], &As[q * 512]);
        }
#pragma unroll
        for (int c = 0; c < 2; c++) {
            const int q = w * 2 + c;
            glds16(&W[(size_t)(n0 + q * 16 + srow) * K + k0 + schunk * 8], &Bs[q * 512]);
        }
        __syncthreads();
        short8 af[MT], bf[4];
#pragma unroll
        for (int mt = 0; mt < MT; mt++)
            af[mt] = *(const short8*)&As[(abase + mt) * 512 + lane * 8];
#pragma unroll
        for (int nt = 0; nt < 4; nt++)
            bf[nt] = *(const short8*)&Bs[(bbase + nt) * 512 + lane * 8];
#pragma unroll
        for (int mt = 0; mt < MT; mt++)
#pragma unroll
            for (int nt = 0; nt < 4; nt++)
                acc[mt][nt] = __builtin_amdgcn_mfma_f32_16x16x32_bf16(af[mt], bf[nt], acc[mt][nt], 0, 0, 0);
    }

#pragma unroll
    for (int mt = 0; mt < MT; mt++) {
#pragma unroll
        for (int nt = 0; nt < 4; nt++) {
            const int n = n0 + wn + nt * 16 + col;
            float bias;
            if constexpr (MODE == 2) bias = b0[n];
            else {
                const int sel = n >> 10, nq = n & 1023;
                bias = (sel == 0 ? b0 : sel == 1 ? b1 : b2)[nq];
            }
#pragma unroll
            for (int r = 0; r < 4; r++) {
                const int m = m0 + wm + mt * 16 + quad * 4 + r;
                const float v = acc[mt][nt][r] + bias;
                if constexpr (MODE == 2) {
                    ((float*)o0)[(size_t)m * 1024 + n] = v;
                } else {
                    const int sel = n >> 10, nq = n & 1023;
                    const int h = nq >> 6, dh = nq & 63, b = m >> 11, t = m & 2047;
                    if (sel < 2) {
                        unsigned short* dst = sel ? (unsigned short*)o1 : (unsigned short*)o0;
                        int tt = t;
                        if (sel == 1) {
                            // K permutation: pos (t16*16 + q*4 + r) <- key (q*8 + t16*4 + r)
                            const int tb = t & 31;
                            tt = (t & ~31) + ((tb & 4) << 2) + ((tb >> 3) << 2) + (tb & 3);
                        }
                        dst[(((size_t)(b * N_HEADS + h)) * SEQ_T + tt) * HEAD_DIM + dh] = f2bf(v);
                    } else {
                        ((unsigned short*)o2)[((size_t)(b * N_HEADS + h) * HEAD_DIM + dh) * SEQ_T + t] = f2bf(v);
                    }
                }
            }
        }
    }
}

// ---------------- flash attention v7: LDS-staged K/V shared by 4 waves ----------------
// (unchanged from round 7)
__global__ __launch_bounds__(256) void flash7(
    const unsigned short* __restrict__ Q,
    const unsigned short* __restrict__ Kp,
    const unsigned short* __restrict__ Vt,
    unsigned short* __restrict__ Y)
{
    __shared__ unsigned short Ks[2][64 * 64];
    __shared__ unsigned short Vs[2][64 * 64];

    const int tid = threadIdx.x;
    const int w = tid >> 6, lane = tid & 63;
    const int col = lane & 15, quad = lane >> 4;
    const int i = blockIdx.x;
    const int bh = (i & 7) * 4 + ((i >> 3) & 3);  // 4 heads per XCD class
    const int qtp = i >> 5;                       // 0..15
    const int b = bh >> 4, h = bh & 15;

    const unsigned short* qbase = Q + (size_t)bh * SEQ_T * HEAD_DIM;
    const unsigned short* kbase = Kp + (size_t)bh * SEQ_T * HEAD_DIM;
    const unsigned short* vbase = Vt + (size_t)bh * HEAD_DIM * SEQ_T;

    const int srow = lane >> 3;
    const int schunk = (lane & 7) ^ srow;
    const int cswz = col & 7;

    const float SC = 0.125f;
    const f32x4 zero = {0.f, 0.f, 0.f, 0.f};

    for (int ti = 0; ti < 2; ti++) {
        const int qt = ti ? (31 - qtp) : qtp;
        const int qrow = qt * 64 + w * 16;
        const short8 qf0 = *(const short8*)&qbase[(size_t)(qrow + col) * HEAD_DIM + quad * 8];
        const short8 qf1 = *(const short8*)&qbase[(size_t)(qrow + col) * HEAD_DIM + quad * 8 + 32];

        f32x4 acc[4];
#pragma unroll
        for (int nt = 0; nt < 4; nt++) acc[nt] = zero;
        float l = 0.f;

        const int nk = qt + 1;

        __syncthreads();
#pragma unroll
        for (int rq = 0; rq < 2; rq++) {
            const int rr = rq * 32 + 8 * w;
            glds16(&kbase[(size_t)(rr + srow) * HEAD_DIM + schunk * 8], &Ks[0][rr * 64]);
            glds16(&vbase[(size_t)(rr + srow) * SEQ_T + schunk * 8], &Vs[0][rr * 64]);
        }

        int cur = 0;
        for (int kt = 0; kt < nk; kt++) {
            const int kb = kt * 64;
            __syncthreads();

            if (kt + 1 < nk) {
                const int kb2 = kb + 64;
#pragma unroll
                for (int rq = 0; rq < 2; rq++) {
                    const int rr = rq * 32 + 8 * w;
                    glds16(&kbase[(size_t)(kb2 + rr + srow) * HEAD_DIM + schunk * 8], &Ks[cur ^ 1][rr * 64]);
                    glds16(&vbase[(size_t)(rr + srow) * SEQ_T + kb2 + schunk * 8], &Vs[cur ^ 1][rr * 64]);
                }
            }

            const unsigned short* ks = Ks[cur];
            const unsigned short* vs = Vs[cur];

            short8 vB[2][4];
#pragma unroll
            for (int g = 0; g < 2; g++)
#pragma unroll
                for (int nt = 0; nt < 4; nt++)
                    vB[g][nt] = *(const short8*)&vs[(nt * 16 + col) * 64 + (((g * 4 + quad) ^ cswz) * 8)];

            f32x4 St[4];
#pragma unroll
            for (int kc = 0; kc < 4; kc++) {
                const short8 kf0 = *(const short8*)&ks[(kc * 16 + col) * 64 + ((quad ^ cswz) * 8)];
                const short8 kf1 = *(const short8*)&ks[(kc * 16 + col) * 64 + (((quad + 4) ^ cswz) * 8)];
                f32x4 z = zero;
                z = __builtin_amdgcn_mfma_f32_16x16x32_bf16(kf0, qf0, z, 0, 0, 0);
                z = __builtin_amdgcn_mfma_f32_16x16x32_bf16(kf1, qf1, z, 0, 0, 0);
                St[kc] = z;
            }

            const bool diag = (kt == nk - 1);
            short8 pA[2];
#pragma unroll
            for (int g = 0; g < 2; g++) {
#pragma unroll
                for (int t16 = 0; t16 < 2; t16++) {
                    const int kc = 2 * g + t16;
                    const int kbase_c = kb + (kc >> 1) * 32 + quad * 8 + (kc & 1) * 4;
#pragma unroll
                    for (int r = 0; r < 4; r++) {
                        float p = __expf(St[kc][r] * SC);
                        if (diag && (kbase_c + r > qrow + col)) p = 0.f;
                        l += p;
                        pA[g][t16 * 4 + r] = (short)f2bf_fast(p);
                    }
                }
            }

#pragma unroll
            for (int g = 0; g < 2; g++)
#pragma unroll
                for (int nt = 0; nt < 4; nt++)
                    acc[nt] = __builtin_amdgcn_mfma_f32_16x16x32_bf16(pA[g], vB[g][nt], acc[nt], 0, 0, 0);

            cur ^= 1;
        }

        l += __shfl_xor(l, 16);
        l += __shfl_xor(l, 32);
        const float linv = 1.0f / l;
        float lr[4];
#pragma unroll
        for (int r = 0; r < 4; r++) lr[r] = __shfl(linv, quad * 4 + r);
#pragma unroll
        for (int nt = 0; nt < 4; nt++)
#pragma unroll
            for (int r = 0; r < 4; r++) {
                const int qg = qrow + quad * 4 + r;
                Y[((size_t)(b * SEQ_T + qg)) * D_MODEL + h * HEAD_DIM + nt * 16 + col] = f2bf(acc[nt][r] * lr[r]);
            }
    }
}

extern "C" void kernel_launch(void* const* d_in, const int* in_sizes, int n_in,
                              void* d_out, int out_size, void* d_ws, size_t ws_size,
                              hipStream_t stream) {
    const float* x  = (const float*)d_in[0];
    const float* Wq = (const float*)d_in[1];
    const float* bq = (const float*)d_in[2];
    const float* Wk = (const float*)d_in[3];
    const float* bk = (const float*)d_in[4];
    const float* Wv = (const float*)d_in[5];
    const float* bv = (const float*)d_in[6];
    const float* Wp = (const float*)d_in[7];
    const float* bp = (const float*)d_in[8];
    float* out = (float*)d_out;

    char* ws = (char*)d_ws;
    const size_t XSZ = (size_t)4096 * 1024 * 2;
    unsigned short* xb  = (unsigned short*)ws;  ws += XSZ;
    unsigned short* wb  = (unsigned short*)ws;  ws += (size_t)3072 * 1024 * 2;
    unsigned short* wpb = (unsigned short*)ws;  ws += (size_t)1024 * 1024 * 2;
    unsigned short* qb  = (unsigned short*)ws;  ws += XSZ;
    unsigned short* kb  = (unsigned short*)ws;  ws += XSZ;  // permuted keys
    unsigned short* vtb = (unsigned short*)ws;  ws += XSZ;
    unsigned short* yb  = (unsigned short*)ws;  ws += XSZ;

    cvt_all<<<8192, 256, 0, stream>>>((const float4*)x, (const float4*)Wq, (const float4*)Wk,
                                      (const float4*)Wv, (const float4*)Wp,
                                      (ushort4*)xb, (ushort4*)wb, (ushort4*)wpb);

    gemm4<3, 128><<<dim3(24, 32), 256, 0, stream>>>(xb, wb, bq, bk, bv, qb, kb, vtb);

    flash7<<<512, 256, 0, stream>>>(qb, kb, vtb, yb);

    gemm4<2, 64><<<dim3(8, 64), 256, 0, stream>>>(yb, wpb, bp, nullptr, nullptr, out, nullptr, nullptr);
}

// Round 10
// 184.786 us; speedup vs baseline: 1.1312x; 1.1312x over previous
//
#include <hip/hip_runtime.h>
#include <math.h>

#define D_MODEL 1024
#define N_HEADS 16
#define HEAD_DIM 64
#define SEQ_T 2048
#define BATCH 2

typedef __attribute__((ext_vector_type(8))) short short8;
typedef __attribute__((ext_vector_type(4))) float f32x4;

__device__ __forceinline__ unsigned short f2bf(float f) {
    union { float f; unsigned int u; } v; v.f = f;
    return (unsigned short)((v.u + 0x7FFFu + ((v.u >> 16) & 1u)) >> 16);
}

// cheap round-half-up pack (P matrix only; values >= 0)
__device__ __forceinline__ unsigned short f2bf_fast(float f) {
    union { float f; unsigned int u; } v; v.f = f;
    return (unsigned short)((v.u + 0x8000u) >> 16);
}

__device__ __forceinline__ void glds16(const unsigned short* g, unsigned short* l) {
    __builtin_amdgcn_global_load_lds(
        (const __attribute__((address_space(1))) unsigned int*)g,
        (__attribute__((address_space(3))) unsigned int*)l, 16, 0, 0);
}

// ---------------- fused fp32 -> bf16 convert (x + 4 weights) ----------------
__global__ void cvt_all(const float4* __restrict__ x,
                        const float4* __restrict__ Wq, const float4* __restrict__ Wk,
                        const float4* __restrict__ Wv, const float4* __restrict__ Wp,
                        ushort4* __restrict__ xb, ushort4* __restrict__ wb,
                        ushort4* __restrict__ wpb) {
    int i = blockIdx.x * 256 + threadIdx.x;
    float4 v; ushort4* dst;
    if (i < 1048576) { v = x[i]; dst = xb + i; }
    else {
        int j = i - 1048576;
        int wsel = j >> 18;
        int o = j & 262143;
        const float4* s = wsel == 0 ? Wq : wsel == 1 ? Wk : wsel == 2 ? Wv : Wp;
        v = s[o];
        dst = (wsel == 3) ? (wpb + o) : (wb + (size_t)wsel * 262144 + o);
    }
    ushort4 u;
    u.x = f2bf(v.x); u.y = f2bf(v.y); u.z = f2bf(v.z); u.w = f2bf(v.w);
    *dst = u;
}

// ---------------- GEMM v5: gemm2 structure + in-group source-chunk XOR swizzle ----------------
// Staging keeps 4-lane groups on one contiguous 64 B segment (coalesced), but permutes which
// lane carries which 16 B chunk: lane i sources chunk (i&3)^((row>>1)&3). Readers fetch row
// col's chunk quad at LDS slot quad^((col>>1)&3) -> per-phase spans cover all 8 four-bank
// groups exactly twice = 2-way = free. Same 16 KB LDS, same barrier structure as gemm2.
// MODE 2: fp32 out row-major [M,1024], bias b0
// MODE 3: fused QKV: N=3072; q [B,H,T,Dh]; k [B,H,Tperm,Dh] (32-key permuted); v [B,H,Dh,T]
template<int MODE, int MTILE>
__global__ __launch_bounds__(256) void gemm5(
    const unsigned short* __restrict__ A,
    const unsigned short* __restrict__ W,
    const float* __restrict__ b0, const float* __restrict__ b1, const float* __restrict__ b2,
    void* __restrict__ o0, void* __restrict__ o1, void* __restrict__ o2)
{
    constexpr int K = 1024;
    constexpr int MT = MTILE / 32;
    constexpr int CAW = MTILE / 64;
    __shared__ unsigned short As[MTILE * 32];
    __shared__ unsigned short Bs[128 * 32];
    const int m0 = blockIdx.y * MTILE;
    const int n0 = blockIdx.x * 128;
    const int tid = threadIdx.x;
    const int w = tid >> 6, lane = tid & 63;
    const int col = lane & 15, quad = lane >> 4;
    const int wm = (w & 1) * (MTILE / 2), wn = (w >> 1) * 64;
    const int lr = lane >> 2;                              // row within 16-row issue
    const int lc = (((lane & 3) ^ ((lr >> 1) & 3))) * 8;   // XOR-permuted source chunk
    const int rswz = (col >> 1) & 3;                       // reader slot swizzle

    const f32x4 zero = {0.f, 0.f, 0.f, 0.f};
    f32x4 acc[MT][4];
#pragma unroll
    for (int i = 0; i < MT; i++)
#pragma unroll
        for (int j = 0; j < 4; j++) acc[i][j] = zero;

    for (int k0 = 0; k0 < K; k0 += 32) {
        __syncthreads();
#pragma unroll
        for (int c = 0; c < CAW; c++) {
            const int q = w * CAW + c;
            glds16(&A[(size_t)(m0 + q * 16 + lr) * K + k0 + lc], &As[q * 512]);
        }
#pragma unroll
        for (int c = 0; c < 2; c++) {
            const int q = w * 2 + c;
            glds16(&W[(size_t)(n0 + q * 16 + lr) * K + k0 + lc], &Bs[q * 512]);
        }
        __syncthreads();
        short8 af[MT], bf[4];
#pragma unroll
        for (int mt = 0; mt < MT; mt++)
            af[mt] = *(const short8*)&As[(wm + mt * 16 + col) * 32 + ((quad ^ rswz) * 8)];
#pragma unroll
        for (int nt = 0; nt < 4; nt++)
            bf[nt] = *(const short8*)&Bs[(wn + nt * 16 + col) * 32 + ((quad ^ rswz) * 8)];
#pragma unroll
        for (int mt = 0; mt < MT; mt++)
#pragma unroll
            for (int nt = 0; nt < 4; nt++)
                acc[mt][nt] = __builtin_amdgcn_mfma_f32_16x16x32_bf16(af[mt], bf[nt], acc[mt][nt], 0, 0, 0);
    }

#pragma unroll
    for (int mt = 0; mt < MT; mt++) {
#pragma unroll
        for (int nt = 0; nt < 4; nt++) {
            const int n = n0 + wn + nt * 16 + col;
            float bias;
            if constexpr (MODE == 2) bias = b0[n];
            else {
                const int sel = n >> 10, nq = n & 1023;
                bias = (sel == 0 ? b0 : sel == 1 ? b1 : b2)[nq];
            }
#pragma unroll
            for (int r = 0; r < 4; r++) {
                const int m = m0 + wm + mt * 16 + quad * 4 + r;
                const float v = acc[mt][nt][r] + bias;
                if constexpr (MODE == 2) {
                    ((float*)o0)[(size_t)m * 1024 + n] = v;
                } else {
                    const int sel = n >> 10, nq = n & 1023;
                    const int h = nq >> 6, dh = nq & 63, b = m >> 11, t = m & 2047;
                    if (sel < 2) {
                        unsigned short* dst = sel ? (unsigned short*)o1 : (unsigned short*)o0;
                        int tt = t;
                        if (sel == 1) {
                            // K permutation: pos (t16*16 + q*4 + r) <- key (q*8 + t16*4 + r)
                            const int tb = t & 31;
                            tt = (t & ~31) + ((tb & 4) << 2) + ((tb >> 3) << 2) + (tb & 3);
                        }
                        dst[(((size_t)(b * N_HEADS + h)) * SEQ_T + tt) * HEAD_DIM + dh] = f2bf(v);
                    } else {
                        ((unsigned short*)o2)[((size_t)(b * N_HEADS + h) * HEAD_DIM + dh) * SEQ_T + t] = f2bf(v);
                    }
                }
            }
        }
    }
}

// ---------------- flash attention v7: LDS-staged K/V shared by 4 waves ----------------
// (unchanged from round 7)
__global__ __launch_bounds__(256) void flash7(
    const unsigned short* __restrict__ Q,
    const unsigned short* __restrict__ Kp,
    const unsigned short* __restrict__ Vt,
    unsigned short* __restrict__ Y)
{
    __shared__ unsigned short Ks[2][64 * 64];
    __shared__ unsigned short Vs[2][64 * 64];

    const int tid = threadIdx.x;
    const int w = tid >> 6, lane = tid & 63;
    const int col = lane & 15, quad = lane >> 4;
    const int i = blockIdx.x;
    const int bh = (i & 7) * 4 + ((i >> 3) & 3);  // 4 heads per XCD class
    const int qtp = i >> 5;                       // 0..15
    const int b = bh >> 4, h = bh & 15;

    const unsigned short* qbase = Q + (size_t)bh * SEQ_T * HEAD_DIM;
    const unsigned short* kbase = Kp + (size_t)bh * SEQ_T * HEAD_DIM;
    const unsigned short* vbase = Vt + (size_t)bh * HEAD_DIM * SEQ_T;

    const int srow = lane >> 3;
    const int schunk = (lane & 7) ^ srow;
    const int cswz = col & 7;

    const float SC = 0.125f;
    const f32x4 zero = {0.f, 0.f, 0.f, 0.f};

    for (int ti = 0; ti < 2; ti++) {
        const int qt = ti ? (31 - qtp) : qtp;
        const int qrow = qt * 64 + w * 16;
        const short8 qf0 = *(const short8*)&qbase[(size_t)(qrow + col) * HEAD_DIM + quad * 8];
        const short8 qf1 = *(const short8*)&qbase[(size_t)(qrow + col) * HEAD_DIM + quad * 8 + 32];

        f32x4 acc[4];
#pragma unroll
        for (int nt = 0; nt < 4; nt++) acc[nt] = zero;
        float l = 0.f;

        const int nk = qt + 1;

        __syncthreads();
#pragma unroll
        for (int rq = 0; rq < 2; rq++) {
            const int rr = rq * 32 + 8 * w;
            glds16(&kbase[(size_t)(rr + srow) * HEAD_DIM + schunk * 8], &Ks[0][rr * 64]);
            glds16(&vbase[(size_t)(rr + srow) * SEQ_T + schunk * 8], &Vs[0][rr * 64]);
        }

        int cur = 0;
        for (int kt = 0; kt < nk; kt++) {
            const int kb = kt * 64;
            __syncthreads();

            if (kt + 1 < nk) {
                const int kb2 = kb + 64;
#pragma unroll
                for (int rq = 0; rq < 2; rq++) {
                    const int rr = rq * 32 + 8 * w;
                    glds16(&kbase[(size_t)(kb2 + rr + srow) * HEAD_DIM + schunk * 8], &Ks[cur ^ 1][rr * 64]);
                    glds16(&vbase[(size_t)(rr + srow) * SEQ_T + kb2 + schunk * 8], &Vs[cur ^ 1][rr * 64]);
                }
            }

            const unsigned short* ks = Ks[cur];
            const unsigned short* vs = Vs[cur];

            short8 vB[2][4];
#pragma unroll
            for (int g = 0; g < 2; g++)
#pragma unroll
                for (int nt = 0; nt < 4; nt++)
                    vB[g][nt] = *(const short8*)&vs[(nt * 16 + col) * 64 + (((g * 4 + quad) ^ cswz) * 8)];

            f32x4 St[4];
#pragma unroll
            for (int kc = 0; kc < 4; kc++) {
                const short8 kf0 = *(const short8*)&ks[(kc * 16 + col) * 64 + ((quad ^ cswz) * 8)];
                const short8 kf1 = *(const short8*)&ks[(kc * 16 + col) * 64 + (((quad + 4) ^ cswz) * 8)];
                f32x4 z = zero;
                z = __builtin_amdgcn_mfma_f32_16x16x32_bf16(kf0, qf0, z, 0, 0, 0);
                z = __builtin_amdgcn_mfma_f32_16x16x32_bf16(kf1, qf1, z, 0, 0, 0);
                St[kc] = z;
            }

            const bool diag = (kt == nk - 1);
            short8 pA[2];
#pragma unroll
            for (int g = 0; g < 2; g++) {
#pragma unroll
                for (int t16 = 0; t16 < 2; t16++) {
                    const int kc = 2 * g + t16;
                    const int kbase_c = kb + (kc >> 1) * 32 + quad * 8 + (kc & 1) * 4;
#pragma unroll
                    for (int r = 0; r < 4; r++) {
                        float p = __expf(St[kc][r] * SC);
                        if (diag && (kbase_c + r > qrow + col)) p = 0.f;
                        l += p;
                        pA[g][t16 * 4 + r] = (short)f2bf_fast(p);
                    }
                }
            }

#pragma unroll
            for (int g = 0; g < 2; g++)
#pragma unroll
                for (int nt = 0; nt < 4; nt++)
                    acc[nt] = __builtin_amdgcn_mfma_f32_16x16x32_bf16(pA[g], vB[g][nt], acc[nt], 0, 0, 0);

            cur ^= 1;
        }

        l += __shfl_xor(l, 16);
        l += __shfl_xor(l, 32);
        const float linv = 1.0f / l;
        float lr[4];
#pragma unroll
        for (int r = 0; r < 4; r++) lr[r] = __shfl(linv, quad * 4 + r);
#pragma unroll
        for (int nt = 0; nt < 4; nt++)
#pragma unroll
            for (int r = 0; r < 4; r++) {
                const int qg = qrow + quad * 4 + r;
                Y[((size_t)(b * SEQ_T + qg)) * D_MODEL + h * HEAD_DIM + nt * 16 + col] = f2bf(acc[nt][r] * lr[r]);
            }
    }
}

extern "C" void kernel_launch(void* const* d_in, const int* in_sizes, int n_in,
                              void* d_out, int out_size, void* d_ws, size_t ws_size,
                              hipStream_t stream) {
    const float* x  = (const float*)d_in[0];
    const float* Wq = (const float*)d_in[1];
    const float* bq = (const float*)d_in[2];
    const float* Wk = (const float*)d_in[3];
    const float* bk = (const float*)d_in[4];
    const float* Wv = (const float*)d_in[5];
    const float* bv = (const float*)d_in[6];
    const float* Wp = (const float*)d_in[7];
    const float* bp = (const float*)d_in[8];
    float* out = (float*)d_out;

    char* ws = (char*)d_ws;
    const size_t XSZ = (size_t)4096 * 1024 * 2;
    unsigned short* xb  = (unsigned short*)ws;  ws += XSZ;
    unsigned short* wb  = (unsigned short*)ws;  ws += (size_t)3072 * 1024 * 2;
    unsigned short* wpb = (unsigned short*)ws;  ws += (size_t)1024 * 1024 * 2;
    unsigned short* qb  = (unsigned short*)ws;  ws += XSZ;
    unsigned short* kb  = (unsigned short*)ws;  ws += XSZ;  // permuted keys
    unsigned short* vtb = (unsigned short*)ws;  ws += XSZ;
    unsigned short* yb  = (unsigned short*)ws;  ws += XSZ;

    cvt_all<<<8192, 256, 0, stream>>>((const float4*)x, (const float4*)Wq, (const float4*)Wk,
                                      (const float4*)Wv, (const float4*)Wp,
                                      (ushort4*)xb, (ushort4*)wb, (ushort4*)wpb);

    gemm5<3, 128><<<dim3(24, 32), 256, 0, stream>>>(xb, wb, bq, bk, bv, qb, kb, vtb);

    flash7<<<512, 256, 0, stream>>>(qb, kb, vtb, yb);

    gemm5<2, 64><<<dim3(8, 64), 256, 0, stream>>>(yb, wpb, bp, nullptr, nullptr, out, nullptr, nullptr);
}